// Round 1
// baseline (340.175 us; speedup 1.0000x reference)
//
#include <hip/hip_runtime.h>

// SSIM over 11x11 gaussian-weighted patches.
// pred: [4, 2048, 16, 121, 3] f32   gt: [2048, 16, 121, 3] f32
// out:  [4, 2048, 16] f32
//
// One thread per output element (v,n,p). Thread streams its contiguous
// 363-float pred block and the matching gt block, keeps 15 accumulators
// (5 stats x 3 channels) in registers, no LDS / no reductions.

static constexpr int N_OUT   = 4 * 2048 * 16;   // 131072
static constexpr int NP_MASK = 2048 * 16 - 1;   // 32767 (N*n_p is pow2)

__device__ __constant__ float G11[11] = {
    0.00102838f, 0.00759875f, 0.03600077f, 0.10936070f, 0.21300555f,
    0.26601173f,
    0.21300555f, 0.10936070f, 0.03600077f, 0.00759875f, 0.00102838f
};

__global__ __launch_bounds__(256) void ssim_kernel(
    const float* __restrict__ pred, const float* __restrict__ gt,
    float* __restrict__ out)
{
    const int o = blockIdx.x * 256 + threadIdx.x;   // [0, 131072)
    const float* p = pred + (size_t)o * 363;
    const float* g = gt   + (size_t)(o & NP_MASK) * 363;

    float mu1[3] = {0.f, 0.f, 0.f};
    float mu2[3] = {0.f, 0.f, 0.f};
    float s1 [3] = {0.f, 0.f, 0.f};
    float s2 [3] = {0.f, 0.f, 0.f};
    float s12[3] = {0.f, 0.f, 0.f};

    #pragma unroll 1
    for (int r = 0; r < 11; ++r) {
        const float wr = G11[r];
        const float* pr = p + r * 33;
        const float* gr = g + r * 33;
        #pragma unroll
        for (int col = 0; col < 11; ++col) {
            const float w = wr * G11[col];
            #pragma unroll
            for (int c = 0; c < 3; ++c) {
                const float pv = pr[col * 3 + c];
                const float gv = gr[col * 3 + c];
                mu1[c] += w * pv;
                mu2[c] += w * gv;
                s1 [c] += w * pv * pv;
                s2 [c] += w * gv * gv;
                s12[c] += w * pv * gv;
            }
        }
    }

    const float C1 = 1e-4f;   // 0.01^2
    const float C2 = 9e-4f;   // 0.03^2
    float acc = 0.f;
    #pragma unroll
    for (int c = 0; c < 3; ++c) {
        const float m1 = mu1[c], m2 = mu2[c];
        const float m1sq = m1 * m1, m2sq = m2 * m2, m12 = m1 * m2;
        const float sig1  = s1[c]  - m1sq;
        const float sig2  = s2[c]  - m2sq;
        const float sg12  = s12[c] - m12;
        const float num = (2.f * m12 + C1) * (2.f * sg12 + C2);
        const float den = (m1sq + m2sq + C1) * (sig1 + sig2 + C2);
        acc += num / den;
    }
    out[o] = acc * (1.f / 3.f);
}

extern "C" void kernel_launch(void* const* d_in, const int* in_sizes, int n_in,
                              void* d_out, int out_size, void* d_ws, size_t ws_size,
                              hipStream_t stream) {
    const float* pred = (const float*)d_in[0];
    const float* gt   = (const float*)d_in[1];
    float* out        = (float*)d_out;
    ssim_kernel<<<N_OUT / 256, 256, 0, stream>>>(pred, gt, out);
}

// Round 3
// 293.773 us; speedup vs baseline: 1.1580x; 1.1580x over previous
//
#include <hip/hip_runtime.h>

// SSIM over 11x11 gaussian-weighted patches — coalesced, 16 lanes/output.
// pred: [4, 2048, 16, 121, 3] f32   gt: [2048, 16, 121, 3] f32
// out:  [4, 2048, 16] f32
//
// Each output (v,n,p) is handled by a 16-lane group; lane = pixel index
// (8 rounds x 16 lanes = 128 >= 121 pixels, zero-padded weights).
// Lane reads 3 consecutive floats (one pixel): a 16-group reads 192
// contiguous bytes. 15 stats reduced over 16 lanes via shfl_xor.
// Block = 256 threads = 16 groups -> grid = N_OUT/16 = 8192 blocks.

static constexpr int N_OUT   = 4 * 2048 * 16;   // 131072
static constexpr int NP_MASK = 2048 * 16 - 1;   // 32767 (N*n_p is pow2)

__device__ __constant__ float G11[11] = {
    0.00102838f, 0.00759875f, 0.03600077f, 0.10936070f, 0.21300555f,
    0.26601173f,
    0.21300555f, 0.10936070f, 0.03600077f, 0.00759875f, 0.00102838f
};

__device__ __forceinline__ float red16(float v) {
    v += __shfl_xor(v, 1);
    v += __shfl_xor(v, 2);
    v += __shfl_xor(v, 4);
    v += __shfl_xor(v, 8);
    return v;
}

__global__ __launch_bounds__(256) void ssim_kernel(
    const float* __restrict__ pred, const float* __restrict__ gt,
    float* __restrict__ out)
{
    __shared__ float W[128];   // 2D gaussian weights, zero-padded past 121
    const int t = threadIdx.x;
    if (t < 128) {
        float w = 0.f;
        if (t < 121) {
            const int r = t / 11;
            const int c = t - r * 11;
            w = G11[r] * G11[c];
        }
        W[t] = w;
    }
    __syncthreads();

    const int lane  = t & 15;
    const int group = t >> 4;                      // 0..15
    const int o     = blockIdx.x * 16 + group;     // output index [0, 131072)
    const float* p = pred + (size_t)o * 363;
    const float* g = gt   + (size_t)(o & NP_MASK) * 363;

    float mu1[3] = {0.f, 0.f, 0.f};
    float mu2[3] = {0.f, 0.f, 0.f};
    float s1 [3] = {0.f, 0.f, 0.f};
    float s2 [3] = {0.f, 0.f, 0.f};
    float s12[3] = {0.f, 0.f, 0.f};

    #pragma unroll
    for (int rnd = 0; rnd < 8; ++rnd) {
        const int pix = lane + rnd * 16;           // 0..127
        const float w = W[pix];                    // 0 for pix >= 121
        const int pc  = (pix < 121 ? pix : 120) * 3;  // clamp: stay in bounds
        const float pv[3] = {p[pc], p[pc + 1], p[pc + 2]};
        const float gv[3] = {g[pc], g[pc + 1], g[pc + 2]};
        #pragma unroll
        for (int c = 0; c < 3; ++c) {
            const float tp = w * pv[c];
            const float tg = w * gv[c];
            mu1[c] += tp;
            mu2[c] += tg;
            s1 [c] = fmaf(tp, pv[c], s1 [c]);
            s2 [c] = fmaf(tg, gv[c], s2 [c]);
            s12[c] = fmaf(tp, gv[c], s12[c]);
        }
    }

    // reduce the 15 stats across the 16-lane group
    #pragma unroll
    for (int c = 0; c < 3; ++c) {
        mu1[c] = red16(mu1[c]);
        mu2[c] = red16(mu2[c]);
        s1 [c] = red16(s1 [c]);
        s2 [c] = red16(s2 [c]);
        s12[c] = red16(s12[c]);
    }

    if (lane == 0) {
        const float C1 = 1e-4f;   // 0.01^2
        const float C2 = 9e-4f;   // 0.03^2
        float acc = 0.f;
        #pragma unroll
        for (int c = 0; c < 3; ++c) {
            const float m1 = mu1[c], m2 = mu2[c];
            const float m1sq = m1 * m1, m2sq = m2 * m2, m12 = m1 * m2;
            const float sig1 = s1[c]  - m1sq;
            const float sig2 = s2[c]  - m2sq;
            const float sg12 = s12[c] - m12;
            const float num = (2.f * m12 + C1) * (2.f * sg12 + C2);
            const float den = (m1sq + m2sq + C1) * (sig1 + sig2 + C2);
            acc += num / den;
        }
        out[o] = acc * (1.f / 3.f);
    }
}

extern "C" void kernel_launch(void* const* d_in, const int* in_sizes, int n_in,
                              void* d_out, int out_size, void* d_ws, size_t ws_size,
                              hipStream_t stream) {
    const float* pred = (const float*)d_in[0];
    const float* gt   = (const float*)d_in[1];
    float* out        = (float*)d_out;
    ssim_kernel<<<N_OUT / 16, 256, 0, stream>>>(pred, gt, out);  // 8192 blocks
}